// Round 1
// baseline (547.682 us; speedup 1.0000x reference)
//
#include <hip/hip_runtime.h>
#include <math.h>

#define H    4096
#define BB   8
#define NN   200
#define NPAD 208
#define EE   400

typedef __bf16 bf16x8 __attribute__((ext_vector_type(8)));
typedef float f32x4 __attribute__((ext_vector_type(4)));

// ---------------- ws layout (bytes) ----------------
#define OFF_NFHI  0u
#define OFF_NFLO  (OFF_NFHI + (unsigned)NPAD*H*2u)   // 1,703,936
#define OFF_QP    (OFF_NFLO + (unsigned)NPAD*H*2u)   // 3,407,872
#define OFF_NPJ   (OFF_QP   + (unsigned)BB*H*4u)     // 3,538,944
#define OFF_AGG   (OFF_NPJ  + (unsigned)NN*H*4u)     // 6,815,744
#define OFF_FALLB (OFF_AGG  + (unsigned)BB*H*4u)
#define OFF_T     (OFF_FALLB+ (unsigned)BB*H*4u)
#define OFF_HB    (OFF_T    + (unsigned)BB*H*4u)
#define OFF_CNT   (OFF_HB   + (unsigned)BB*H*4u)     // 7,340,032
#define OFF_NPJP  (OFF_CNT  + 64u)                   // 7,340,096 (16B aligned)

__device__ __forceinline__ unsigned short f2bf(float x) {
  unsigned int u = __float_as_uint(x);
  u = (u + 0x7fffu + ((u >> 16) & 1u)) >> 16;
  return (unsigned short)u;
}
__device__ __forceinline__ float bf2f(unsigned short b) {
  return __uint_as_float(((unsigned int)b) << 16);
}
__device__ __forceinline__ bf16x8 ld_bf8(const unsigned short* p) {
  union { uint4 u; bf16x8 v; } x;
  x.u = *(const uint4*)p;
  return x.v;
}

// ---------- 1. split node_features into bf16 hi/lo (pad rows 200..207 = 0) ----------
__global__ __launch_bounds__(256) void k_split_nf(const float* __restrict__ nf,
                                                  unsigned short* __restrict__ hi,
                                                  unsigned short* __restrict__ lo) {
  int i = blockIdx.x * 256 + threadIdx.x;        // over NPAD*H/4 = 212992
  int row = i >> 10;
  int c4 = (i & 1023) * 4;
  float4 v = make_float4(0.f, 0.f, 0.f, 0.f);
  if (row < NN) v = *(const float4*)&nf[(size_t)row * H + c4];
  float xs[4] = {v.x, v.y, v.z, v.w};
  ushort4 hv, lv;
  unsigned short* hp = &hv.x;
  unsigned short* lp = &lv.x;
#pragma unroll
  for (int j = 0; j < 4; j++) {
    unsigned short h = f2bf(xs[j]);
    hp[j] = h;
    lp[j] = f2bf(xs[j] - bf2f(h));
  }
  *(ushort4*)&hi[(size_t)row * H + c4] = hv;
  *(ushort4*)&lo[(size_t)row * H + c4] = lv;
}

// ---------- 2. generic M=8 GEMM: Y[m][h] = sum_k X[m][k]*W[h][k] + b[h] ----------
// grid 512 x 256: each wave handles 2 rows of W; lanes stride k by float4.
__global__ __launch_bounds__(256) void k_gemm_m8(const float* __restrict__ X,
                                                 const float* __restrict__ W,
                                                 const float* __restrict__ bias,
                                                 float* __restrict__ Y, int relu) {
  const int wave = (blockIdx.x * 256 + threadIdx.x) >> 6;  // 0..2047
  const int lane = threadIdx.x & 63;
  const int h0 = wave * 2;
  float acc0[8] = {0, 0, 0, 0, 0, 0, 0, 0};
  float acc1[8] = {0, 0, 0, 0, 0, 0, 0, 0};
  const float4* Wr0 = (const float4*)(W + (size_t)h0 * H);
  const float4* Wr1 = (const float4*)(W + (size_t)(h0 + 1) * H);
  const float4* Xv = (const float4*)X;
#pragma unroll 4
  for (int j = 0; j < 16; j++) {
    const int kq = lane + j * 64;
    float4 w0 = Wr0[kq];
    float4 w1 = Wr1[kq];
#pragma unroll
    for (int m = 0; m < 8; m++) {
      float4 x = Xv[m * (H / 4) + kq];
      acc0[m] = fmaf(w0.x, x.x, acc0[m]);
      acc0[m] = fmaf(w0.y, x.y, acc0[m]);
      acc0[m] = fmaf(w0.z, x.z, acc0[m]);
      acc0[m] = fmaf(w0.w, x.w, acc0[m]);
      acc1[m] = fmaf(w1.x, x.x, acc1[m]);
      acc1[m] = fmaf(w1.y, x.y, acc1[m]);
      acc1[m] = fmaf(w1.z, x.z, acc1[m]);
      acc1[m] = fmaf(w1.w, x.w, acc1[m]);
    }
  }
#pragma unroll
  for (int m = 0; m < 8; m++) {
    float a0 = acc0[m], a1 = acc1[m];
#pragma unroll
    for (int off = 32; off > 0; off >>= 1) {
      a0 += __shfl_xor(a0, off, 64);
      a1 += __shfl_xor(a1, off, 64);
    }
    if (lane == 0) {
      float y0 = a0 + bias[h0];
      float y1 = a1 + bias[h0 + 1];
      if (relu) { y0 = fmaxf(y0, 0.f); y1 = fmaxf(y1, 0.f); }
      Y[(size_t)m * H + h0] = y0;
      Y[(size_t)m * H + h0 + 1] = y1;
    }
  }
}

// ---------- 3. npj partial GEMM via split-bf16 3-pass MFMA ----------
// grid (64 * ks) x 256. block: 64 output cols (h), k-range nchunks*64.
// waves: hseg = wid&1 (32-col half), nseg = wid>>1 (7 n-tiles, overlapping tile 6).
__global__ __launch_bounds__(256) void k_npj_mfma(const unsigned short* __restrict__ nfhi,
                                                  const unsigned short* __restrict__ nflo,
                                                  const float* __restrict__ Wn,
                                                  float* __restrict__ npjp, int nchunks) {
  __shared__ __align__(16) unsigned short Ahi[NPAD * 72];
  __shared__ __align__(16) unsigned short Alo[NPAD * 72];
  __shared__ __align__(16) unsigned short Bhi[64 * 72];
  __shared__ __align__(16) unsigned short Blo[64 * 72];
  const int hblk = blockIdx.x & 63;
  const int kblk = blockIdx.x >> 6;
  const int h0 = hblk * 64;
  const int kbase = kblk * (nchunks * 64);
  const int tid = threadIdx.x;
  const int wid = tid >> 6, lane = tid & 63;
  const int hseg = wid & 1, nseg = wid >> 1;
  const int lrow = lane & 15, lk8 = (lane >> 4) * 8;

  f32x4 acc[7][2];
#pragma unroll
  for (int nt = 0; nt < 7; nt++)
#pragma unroll
    for (int ht = 0; ht < 2; ht++) {
      f32x4 z = {0.f, 0.f, 0.f, 0.f};
      acc[nt][ht] = z;
    }

  for (int ck = 0; ck < nchunks; ck++) {
    const int k0 = kbase + ck * 64;
    __syncthreads();  // protect previous iteration's LDS reads
    // stage A: NPAD x 64 bf16, padded stride 72 (144B -> 2-way-free banks)
#pragma unroll
    for (int i = 0; i < 7; i++) {
      int idx = tid + i * 256;  // < 1664
      if (idx < (NPAD * 64 / 8)) {
        int row = idx >> 3, c8 = (idx & 7) * 8;
        *(uint4*)&Ahi[row * 72 + c8] = *(const uint4*)&nfhi[(size_t)row * H + k0 + c8];
        *(uint4*)&Alo[row * 72 + c8] = *(const uint4*)&nflo[(size_t)row * H + k0 + c8];
      }
    }
    // stage B: Wn rows h0..h0+63, cols k0..k0+63, f32 -> hi/lo bf16
#pragma unroll
    for (int i = 0; i < 4; i++) {
      int idx = tid + i * 256;  // < 1024
      int row = idx >> 4, c4 = (idx & 15) * 4;
      float4 w = *(const float4*)&Wn[(size_t)(h0 + row) * H + k0 + c4];
      float xs[4] = {w.x, w.y, w.z, w.w};
      ushort4 hv, lv;
      unsigned short* hp = &hv.x;
      unsigned short* lp = &lv.x;
#pragma unroll
      for (int j = 0; j < 4; j++) {
        unsigned short hb = f2bf(xs[j]);
        hp[j] = hb;
        lp[j] = f2bf(xs[j] - bf2f(hb));
      }
      *(ushort4*)&Bhi[row * 72 + c4] = hv;
      *(ushort4*)&Blo[row * 72 + c4] = lv;
    }
    __syncthreads();
    // MFMA: D[n][h], A = NF rows, B[k][h] = Wn[h][k]
#pragma unroll
    for (int kf = 0; kf < 2; kf++) {
      const int ko = kf * 32 + lk8;
      bf16x8 bh[2], bl[2];
#pragma unroll
      for (int ht = 0; ht < 2; ht++) {
        int hcol = hseg * 32 + ht * 16 + lrow;
        bh[ht] = ld_bf8(&Bhi[hcol * 72 + ko]);
        bl[ht] = ld_bf8(&Blo[hcol * 72 + ko]);
      }
#pragma unroll
      for (int nt = 0; nt < 7; nt++) {
        int nrow = (nseg * 6 + nt) * 16 + lrow;
        bf16x8 ah = ld_bf8(&Ahi[nrow * 72 + ko]);
        bf16x8 al = ld_bf8(&Alo[nrow * 72 + ko]);
#pragma unroll
        for (int ht = 0; ht < 2; ht++) {
          acc[nt][ht] = __builtin_amdgcn_mfma_f32_16x16x32_bf16(ah, bh[ht], acc[nt][ht], 0, 0, 0);
          acc[nt][ht] = __builtin_amdgcn_mfma_f32_16x16x32_bf16(ah, bl[ht], acc[nt][ht], 0, 0, 0);
          acc[nt][ht] = __builtin_amdgcn_mfma_f32_16x16x32_bf16(al, bh[ht], acc[nt][ht], 0, 0, 0);
        }
      }
    }
  }
  // epilogue: write partials (bias added in reduce). nseg1 skips its overlap tile.
#pragma unroll
  for (int nt = 0; nt < 7; nt++) {
    if (nseg == 1 && nt == 0) continue;
#pragma unroll
    for (int ht = 0; ht < 2; ht++) {
      int h = h0 + hseg * 32 + ht * 16 + lrow;
#pragma unroll
      for (int r = 0; r < 4; r++) {
        int n = (nseg * 6 + nt) * 16 + (lane >> 4) * 4 + r;
        if (n < NN) npjp[((size_t)kblk * NN + n) * H + h] = acc[nt][ht][r];
      }
    }
  }
}

// ---------- 4. reduce k-split partials + bias ----------
__global__ __launch_bounds__(256) void k_npj_reduce(const float* __restrict__ npjp,
                                                    const float* __restrict__ bn,
                                                    float* __restrict__ npj, int ks) {
  int e = blockIdx.x * 256 + threadIdx.x;  // < NN*H
  float s = bn[e & (H - 1)];
  for (int kb = 0; kb < ks; kb++) s += npjp[(size_t)kb * NN * H + e];
  npj[e] = s;
}

// ---------- 5. per-batch: sim ranking + top3 + edge scan + agg + fallback ----------
__global__ __launch_bounds__(256) void k_select(const float* __restrict__ qp,
                                                const float* __restrict__ npj,
                                                const float* __restrict__ nf,
                                                const int* __restrict__ edge,
                                                const int* __restrict__ batch,
                                                float* __restrict__ agg,
                                                float* __restrict__ fallb,
                                                int* __restrict__ cntout) {
  const int b = blockIdx.x;
  const int tid = threadIdx.x;
  const int wid = tid >> 6, lane = tid & 63;
  __shared__ float key[NN];
  __shared__ int starts[3], firsts[3], dsts[3], list[NN];
  __shared__ int cnt_s, cntn_s;

  if (tid < 3) firsts[tid] = EE;

  // rank key: (qp[b]·npj[n]) * rsqrt(||npj[n]||^2); qn>0 divides out of ranking
  for (int n = wid; n < NN; n += 4) {
    float num = 0.f, nn2 = 0.f;
#pragma unroll 4
    for (int i = 0; i < 16; i++) {
      int kq = lane + i * 64;
      float4 p = *(const float4*)&npj[(size_t)n * H + kq * 4];
      float4 q = *(const float4*)&qp[(size_t)b * H + kq * 4];
      num = fmaf(p.x, q.x, num); num = fmaf(p.y, q.y, num);
      num = fmaf(p.z, q.z, num); num = fmaf(p.w, q.w, num);
      nn2 = fmaf(p.x, p.x, nn2); nn2 = fmaf(p.y, p.y, nn2);
      nn2 = fmaf(p.z, p.z, nn2); nn2 = fmaf(p.w, p.w, nn2);
    }
#pragma unroll
    for (int off = 32; off > 0; off >>= 1) {
      num += __shfl_xor(num, off, 64);
      nn2 += __shfl_xor(nn2, off, 64);
    }
    if (lane == 0)
      key[n] = (batch[n] == b) ? num * rsqrtf(fmaxf(nn2, 1e-30f)) : -INFINITY;
  }
  __syncthreads();

  if (tid == 0) {
    // deterministic batch-node list
    int c = 0;
    for (int n = 0; n < NN; n++)
      if (batch[n] == b) list[c++] = n;
    cntn_s = c;
    // stable top-3 (strict > keeps lowest index on ties, matching lax.top_k)
    int s0 = -1, s1 = -1, s2 = -1;
    for (int s = 0; s < 3; s++) {
      float best = -INFINITY;
      int bi = -1;
      for (int n = 0; n < NN; n++) {
        if (n == s0 || n == s1 || n == s2) continue;
        float v = key[n];
        if (v > best) { best = v; bi = n; }
      }
      if (bi < 0) {  // all remaining are -inf: take lowest unchosen index
        for (int n = 0; n < NN; n++)
          if (n != s0 && n != s1 && n != s2) { bi = n; break; }
      }
      if (s == 0) s0 = bi; else if (s == 1) s1 = bi; else s2 = bi;
      starts[s] = bi;
    }
  }
  __syncthreads();

  // first valid outgoing edge per start
  for (int e = tid; e < EE; e += 256) {
    int s = edge[e];
    int d = edge[EE + e];
    if (batch[d] == b) {
#pragma unroll
      for (int j = 0; j < 3; j++)
        if (s == starts[j]) atomicMin(&firsts[j], e);
    }
  }
  __syncthreads();

  if (tid == 0) {
    int c = 0;
#pragma unroll
    for (int j = 0; j < 3; j++) {
      int f = firsts[j];
      dsts[j] = edge[EE + (f < EE ? f : EE - 1)];
      c += (f < EE) ? 1 : 0;
    }
    cnt_s = c;
    cntout[b] = c;
  }
  __syncthreads();

  const float invc = 1.f / (float)(cnt_s > 0 ? cnt_s : 1);
  const float invn = 1.f / (float)(cntn_s > 0 ? cntn_s : 1);
  const int cn = cntn_s;
  for (int col = tid; col < H; col += 256) {
    float a = 0.f;
#pragma unroll
    for (int j = 0; j < 3; j++)
      if (firsts[j] < EE)
        a += 0.5f * (nf[(size_t)starts[j] * H + col] + nf[(size_t)dsts[j] * H + col]);
    agg[(size_t)b * H + col] = a * invc;
    float f = 0.f;
    for (int i = 0; i < cn; i++) f += npj[(size_t)list[i] * H + col];
    fallb[(size_t)b * H + col] = f * invn;
  }
}

// ---------- 6. select h vs fallback, LayerNorm, write out ----------
__global__ __launch_bounds__(256) void k_finalize(const float* __restrict__ hb,
                                                  const float* __restrict__ fallb,
                                                  const int* __restrict__ cnt,
                                                  const float* __restrict__ g,
                                                  const float* __restrict__ beta,
                                                  float* __restrict__ out) {
  const int b = blockIdx.x;
  const int tid = threadIdx.x;
  const int wid = tid >> 6, lane = tid & 63;
  __shared__ float red[4];
  const float* src = (cnt[b] > 0) ? &hb[(size_t)b * H] : &fallb[(size_t)b * H];
  float v[16];
  float s = 0.f;
#pragma unroll
  for (int i = 0; i < 16; i++) {
    v[i] = src[tid + i * 256];
    s += v[i];
  }
#pragma unroll
  for (int off = 32; off > 0; off >>= 1) s += __shfl_xor(s, off, 64);
  if (lane == 0) red[wid] = s;
  __syncthreads();
  float mu = (red[0] + red[1] + red[2] + red[3]) * (1.f / H);
  float q = 0.f;
#pragma unroll
  for (int i = 0; i < 16; i++) {
    float d = v[i] - mu;
    q = fmaf(d, d, q);
  }
  __syncthreads();  // red reuse
#pragma unroll
  for (int off = 32; off > 0; off >>= 1) q += __shfl_xor(q, off, 64);
  if (lane == 0) red[wid] = q;
  __syncthreads();
  float var = (red[0] + red[1] + red[2] + red[3]) * (1.f / H);
  float inv = 1.f / sqrtf(var + 1e-5f);
#pragma unroll
  for (int i = 0; i < 16; i++) {
    int col = tid + i * 256;
    out[(size_t)b * H + col] = (v[i] - mu) * inv * g[col] + beta[col];
  }
}

extern "C" void kernel_launch(void* const* d_in, const int* in_sizes, int n_in,
                              void* d_out, int out_size, void* d_ws, size_t ws_size,
                              hipStream_t stream) {
  (void)in_sizes; (void)n_in; (void)out_size;
  const float* query = (const float*)d_in[0];
  const float* nf    = (const float*)d_in[1];
  const float* Wq = (const float*)d_in[2];
  const float* bq = (const float*)d_in[3];
  const float* Wn = (const float*)d_in[4];
  const float* bn = (const float*)d_in[5];
  const float* W1 = (const float*)d_in[6];
  const float* b1 = (const float*)d_in[7];
  const float* W2 = (const float*)d_in[8];
  const float* b2 = (const float*)d_in[9];
  const float* lng = (const float*)d_in[10];
  const float* lnb = (const float*)d_in[11];
  const int* edge  = (const int*)d_in[12];
  const int* batch = (const int*)d_in[13];

  char* ws = (char*)d_ws;
  unsigned short* nfhi = (unsigned short*)(ws + OFF_NFHI);
  unsigned short* nflo = (unsigned short*)(ws + OFF_NFLO);
  float* qp    = (float*)(ws + OFF_QP);
  float* npj   = (float*)(ws + OFF_NPJ);
  float* agg   = (float*)(ws + OFF_AGG);
  float* fallb = (float*)(ws + OFF_FALLB);
  float* tbuf  = (float*)(ws + OFF_T);
  float* hbuf  = (float*)(ws + OFF_HB);
  int*   cnt   = (int*)(ws + OFF_CNT);
  float* npjp  = (float*)(ws + OFF_NPJP);

  // k-split factor limited by available workspace (4096 must divide ks*64)
  size_t per = (size_t)NN * H * 4u;
  int ks = 1;
  if (ws_size >= (size_t)OFF_NPJP + 4 * per) ks = 4;
  else if (ws_size >= (size_t)OFF_NPJP + 2 * per) ks = 2;
  int nchunks = 64 / ks;

  k_split_nf<<<dim3(NPAD * (H / 4) / 256), dim3(256), 0, stream>>>(nf, nfhi, nflo);
  k_gemm_m8<<<dim3(512), dim3(256), 0, stream>>>(query, Wq, bq, qp, 0);
  k_npj_mfma<<<dim3(64 * ks), dim3(256), 0, stream>>>(nfhi, nflo, Wn, npjp, nchunks);
  k_npj_reduce<<<dim3(NN * H / 256), dim3(256), 0, stream>>>(npjp, bn, npj, ks);
  k_select<<<dim3(BB), dim3(256), 0, stream>>>(qp, npj, nf, edge, batch, agg, fallb, cnt);
  k_gemm_m8<<<dim3(512), dim3(256), 0, stream>>>(agg, W1, b1, tbuf, 1);
  k_gemm_m8<<<dim3(512), dim3(256), 0, stream>>>(tbuf, W2, b2, hbuf, 0);
  k_finalize<<<dim3(BB), dim3(256), 0, stream>>>(hbuf, fallb, cnt, lng, lnb, (float*)d_out);
}

// Round 2
// 367.191 us; speedup vs baseline: 1.4915x; 1.4915x over previous
//
#include <hip/hip_runtime.h>
#include <math.h>

#define H    4096
#define BB   8
#define NN   200
#define NPAD 208
#define EE   400

typedef __bf16 bf16x8 __attribute__((ext_vector_type(8)));
typedef float f32x4 __attribute__((ext_vector_type(4)));

// ---------------- ws layout (bytes) ----------------
#define OFF_NFHI  0u
#define OFF_NFLO  (OFF_NFHI + (unsigned)NPAD*H*2u)   // 1,703,936
#define OFF_QP    (OFF_NFLO + (unsigned)NPAD*H*2u)   // 3,407,872
#define OFF_NPJ   (OFF_QP   + (unsigned)BB*H*4u)     // 3,538,944
#define OFF_AGG   (OFF_NPJ  + (unsigned)NN*H*4u)     // 6,815,744
#define OFF_FALLB (OFF_AGG  + (unsigned)BB*H*4u)
#define OFF_T     (OFF_FALLB+ (unsigned)BB*H*4u)
#define OFF_HB    (OFF_T    + (unsigned)BB*H*4u)
#define OFF_KEY   (OFF_HB   + (unsigned)BB*H*4u)     // 7,340,032  B*NN*4
#define OFF_META  (OFF_KEY  + (unsigned)BB*NN*4u)    // +6400      B*16*4
#define OFF_LIST  (OFF_META + (unsigned)BB*16*4u)    // +512       B*NN*4
#define OFF_NPJP  (OFF_LIST + (unsigned)BB*NN*4u)    // 7,353,344 (16B aligned)

__device__ __forceinline__ unsigned short f2bf(float x) {
  unsigned int u = __float_as_uint(x);
  u = (u + 0x7fffu + ((u >> 16) & 1u)) >> 16;
  return (unsigned short)u;
}
__device__ __forceinline__ float bf2f(unsigned short b) {
  return __uint_as_float(((unsigned int)b) << 16);
}
__device__ __forceinline__ bf16x8 ld_bf8(const unsigned short* p) {
  union { uint4 u; bf16x8 v; } x;
  x.u = *(const uint4*)p;
  return x.v;
}

// ---------- 1. split node_features into bf16 hi/lo (pad rows 200..207 = 0) ----------
__global__ __launch_bounds__(256) void k_split_nf(const float* __restrict__ nf,
                                                  unsigned short* __restrict__ hi,
                                                  unsigned short* __restrict__ lo) {
  int i = blockIdx.x * 256 + threadIdx.x;        // over NPAD*H/4 = 212992
  int row = i >> 10;
  int c4 = (i & 1023) * 4;
  float4 v = make_float4(0.f, 0.f, 0.f, 0.f);
  if (row < NN) v = *(const float4*)&nf[(size_t)row * H + c4];
  float xs[4] = {v.x, v.y, v.z, v.w};
  ushort4 hv, lv;
  unsigned short* hp = &hv.x;
  unsigned short* lp = &lv.x;
#pragma unroll
  for (int j = 0; j < 4; j++) {
    unsigned short h = f2bf(xs[j]);
    hp[j] = h;
    lp[j] = f2bf(xs[j] - bf2f(h));
  }
  *(ushort4*)&hi[(size_t)row * H + c4] = hv;
  *(ushort4*)&lo[(size_t)row * H + c4] = lv;
}

// ---------- 2. generic M=8 GEMM: Y[m][h] = sum_k X[m][k]*W[h][k] + b[h] ----------
__global__ __launch_bounds__(256) void k_gemm_m8(const float* __restrict__ X,
                                                 const float* __restrict__ W,
                                                 const float* __restrict__ bias,
                                                 float* __restrict__ Y, int relu) {
  const int wave = (blockIdx.x * 256 + threadIdx.x) >> 6;  // 0..2047
  const int lane = threadIdx.x & 63;
  const int h0 = wave * 2;
  float acc0[8] = {0, 0, 0, 0, 0, 0, 0, 0};
  float acc1[8] = {0, 0, 0, 0, 0, 0, 0, 0};
  const float4* Wr0 = (const float4*)(W + (size_t)h0 * H);
  const float4* Wr1 = (const float4*)(W + (size_t)(h0 + 1) * H);
  const float4* Xv = (const float4*)X;
#pragma unroll 4
  for (int j = 0; j < 16; j++) {
    const int kq = lane + j * 64;
    float4 w0 = Wr0[kq];
    float4 w1 = Wr1[kq];
#pragma unroll
    for (int m = 0; m < 8; m++) {
      float4 x = Xv[m * (H / 4) + kq];
      acc0[m] = fmaf(w0.x, x.x, acc0[m]);
      acc0[m] = fmaf(w0.y, x.y, acc0[m]);
      acc0[m] = fmaf(w0.z, x.z, acc0[m]);
      acc0[m] = fmaf(w0.w, x.w, acc0[m]);
      acc1[m] = fmaf(w1.x, x.x, acc1[m]);
      acc1[m] = fmaf(w1.y, x.y, acc1[m]);
      acc1[m] = fmaf(w1.z, x.z, acc1[m]);
      acc1[m] = fmaf(w1.w, x.w, acc1[m]);
    }
  }
#pragma unroll
  for (int m = 0; m < 8; m++) {
    float a0 = acc0[m], a1 = acc1[m];
#pragma unroll
    for (int off = 32; off > 0; off >>= 1) {
      a0 += __shfl_xor(a0, off, 64);
      a1 += __shfl_xor(a1, off, 64);
    }
    if (lane == 0) {
      float y0 = a0 + bias[h0];
      float y1 = a1 + bias[h0 + 1];
      if (relu) { y0 = fmaxf(y0, 0.f); y1 = fmaxf(y1, 0.f); }
      Y[(size_t)m * H + h0] = y0;
      Y[(size_t)m * H + h0 + 1] = y1;
    }
  }
}

// ---------- 3. npj partial GEMM via split-bf16 3-pass MFMA, 8 waves/block ----------
// grid (64 * ks) x 512. block: 64 output cols (h), k-range nchunks*64.
// waves: hseg = wid&1 (32-col half), nseg = wid>>1 (n-tiles {3,3,3,4} of 13).
__global__ __launch_bounds__(512, 4) void k_npj_mfma(const unsigned short* __restrict__ nfhi,
                                                     const unsigned short* __restrict__ nflo,
                                                     const float* __restrict__ Wn,
                                                     float* __restrict__ npjp, int nchunks) {
  __shared__ __align__(16) unsigned short Ahi[NPAD * 72];
  __shared__ __align__(16) unsigned short Alo[NPAD * 72];
  __shared__ __align__(16) unsigned short Bhi[64 * 72];
  __shared__ __align__(16) unsigned short Blo[64 * 72];
  const int hblk = blockIdx.x & 63;
  const int kblk = blockIdx.x >> 6;
  const int h0 = hblk * 64;
  const int kbase = kblk * (nchunks * 64);
  const int tid = threadIdx.x;
  const int wid = tid >> 6, lane = tid & 63;
  const int hseg = wid & 1, nseg = wid >> 1;   // nseg 0..3
  const int lrow = lane & 15, lk8 = (lane >> 4) * 8;

  f32x4 acc[4][2];
#pragma unroll
  for (int t = 0; t < 4; t++)
#pragma unroll
    for (int ht = 0; ht < 2; ht++) {
      f32x4 z = {0.f, 0.f, 0.f, 0.f};
      acc[t][ht] = z;
    }

  for (int ck = 0; ck < nchunks; ck++) {
    const int k0 = kbase + ck * 64;
    __syncthreads();  // protect previous iteration's LDS reads
    // stage A: NPAD x 64 bf16 (hi+lo), padded stride 72
#pragma unroll
    for (int i = 0; i < 4; i++) {
      int idx = tid + i * 512;  // < 2048, need < 1664
      if (idx < (NPAD * 64 / 8)) {
        int row = idx >> 3, c8 = (idx & 7) * 8;
        *(uint4*)&Ahi[row * 72 + c8] = *(const uint4*)&nfhi[(size_t)row * H + k0 + c8];
        *(uint4*)&Alo[row * 72 + c8] = *(const uint4*)&nflo[(size_t)row * H + k0 + c8];
      }
    }
    // stage B: Wn rows h0..h0+63, cols k0..k0+63, f32 -> hi/lo bf16
#pragma unroll
    for (int i = 0; i < 2; i++) {
      int idx = tid + i * 512;  // < 1024
      if (idx < 1024) {
        int row = idx >> 4, c4 = (idx & 15) * 4;
        float4 w = *(const float4*)&Wn[(size_t)(h0 + row) * H + k0 + c4];
        float xs[4] = {w.x, w.y, w.z, w.w};
        ushort4 hv, lv;
        unsigned short* hp = &hv.x;
        unsigned short* lp = &lv.x;
#pragma unroll
        for (int j = 0; j < 4; j++) {
          unsigned short hb = f2bf(xs[j]);
          hp[j] = hb;
          lp[j] = f2bf(xs[j] - bf2f(hb));
        }
        *(ushort4*)&Bhi[row * 72 + c4] = hv;
        *(ushort4*)&Blo[row * 72 + c4] = lv;
      }
    }
    __syncthreads();
    // MFMA: D[n][h], A = NF rows, B[k][h] = Wn[h][k]
#pragma unroll
    for (int kf = 0; kf < 2; kf++) {
      const int ko = kf * 32 + lk8;
      bf16x8 bh[2], bl[2];
#pragma unroll
      for (int ht = 0; ht < 2; ht++) {
        int hcol = hseg * 32 + ht * 16 + lrow;
        bh[ht] = ld_bf8(&Bhi[hcol * 72 + ko]);
        bl[ht] = ld_bf8(&Blo[hcol * 72 + ko]);
      }
#pragma unroll
      for (int t = 0; t < 4; t++) {
        if (t == 3 && nseg < 3) continue;   // only nseg3 owns a 4th tile
        int tile = nseg * 3 + t;            // 0..12
        int nrow = tile * 16 + lrow;
        bf16x8 ah = ld_bf8(&Ahi[nrow * 72 + ko]);
        bf16x8 al = ld_bf8(&Alo[nrow * 72 + ko]);
#pragma unroll
        for (int ht = 0; ht < 2; ht++) {
          acc[t][ht] = __builtin_amdgcn_mfma_f32_16x16x32_bf16(ah, bh[ht], acc[t][ht], 0, 0, 0);
          acc[t][ht] = __builtin_amdgcn_mfma_f32_16x16x32_bf16(ah, bl[ht], acc[t][ht], 0, 0, 0);
          acc[t][ht] = __builtin_amdgcn_mfma_f32_16x16x32_bf16(al, bh[ht], acc[t][ht], 0, 0, 0);
        }
      }
    }
  }
  // epilogue: write partials (bias added in reduce)
#pragma unroll
  for (int t = 0; t < 4; t++) {
    if (t == 3 && nseg < 3) continue;
    int tile = nseg * 3 + t;
#pragma unroll
    for (int ht = 0; ht < 2; ht++) {
      int h = h0 + hseg * 32 + ht * 16 + lrow;
#pragma unroll
      for (int r = 0; r < 4; r++) {
        int n = tile * 16 + (lane >> 4) * 4 + r;
        if (n < NN) npjp[((size_t)kblk * NN + n) * H + h] = acc[t][ht][r];
      }
    }
  }
}

// ---------- 4. reduce k-split partials + bias ----------
__global__ __launch_bounds__(256) void k_npj_reduce(const float* __restrict__ npjp,
                                                    const float* __restrict__ bn,
                                                    float* __restrict__ npj, int ks) {
  int e = blockIdx.x * 256 + threadIdx.x;  // < NN*H
  float s = bn[e & (H - 1)];
  for (int kb = 0; kb < ks; kb++) s += npjp[(size_t)kb * NN * H + e];
  npj[e] = s;
}

// ---------- 5a. per-node rank keys: one block per node, all 8 batches ----------
__global__ __launch_bounds__(256) void k_sim(const float* __restrict__ qp,
                                             const float* __restrict__ npj,
                                             const int* __restrict__ batch,
                                             float* __restrict__ key) {
  const int n = blockIdx.x;
  const int tid = threadIdx.x, lane = tid & 63, wid = tid >> 6;
  __shared__ float red[4 * 9];
  __shared__ float fin[9];
  const float4* pv = (const float4*)(npj + (size_t)n * H);
  const float4* qv = (const float4*)qp;
  float acc[9];
#pragma unroll
  for (int j = 0; j < 9; j++) acc[j] = 0.f;
#pragma unroll
  for (int i = 0; i < 4; i++) {
    float4 p = pv[tid + i * 256];
    acc[0] = fmaf(p.x, p.x, fmaf(p.y, p.y, fmaf(p.z, p.z, fmaf(p.w, p.w, acc[0]))));
#pragma unroll
    for (int b = 0; b < 8; b++) {
      float4 q = qv[b * (H / 4) + tid + i * 256];
      acc[1 + b] = fmaf(p.x, q.x, fmaf(p.y, q.y, fmaf(p.z, q.z, fmaf(p.w, q.w, acc[1 + b]))));
    }
  }
#pragma unroll
  for (int j = 0; j < 9; j++)
#pragma unroll
    for (int off = 32; off > 0; off >>= 1) acc[j] += __shfl_xor(acc[j], off, 64);
  if (lane == 0)
#pragma unroll
    for (int j = 0; j < 9; j++) red[wid * 9 + j] = acc[j];
  __syncthreads();
  if (tid < 9) fin[tid] = red[0 * 9 + tid] + red[1 * 9 + tid] + red[2 * 9 + tid] + red[3 * 9 + tid];
  __syncthreads();
  if (tid < 8) {
    float r = rsqrtf(fmaxf(fin[0], 1e-30f));
    key[tid * NN + n] = (batch[n] == tid) ? fin[1 + tid] * r : -INFINITY;
  }
}

// ---------- 5b. per-batch: wave-parallel top3 + edge scan + list ----------
__global__ __launch_bounds__(256) void k_topedges(const float* __restrict__ key,
                                                  const int* __restrict__ edge,
                                                  const int* __restrict__ batch,
                                                  int* __restrict__ meta,
                                                  int* __restrict__ list) {
  const int b = blockIdx.x;
  const int tid = threadIdx.x, lane = tid & 63, wid = tid >> 6;
  __shared__ float key_s[256];
  __shared__ int starts_s[3], firsts_s[3];
  __shared__ float redv[4];
  __shared__ int redi[4];
  key_s[tid] = (tid < NN) ? key[b * NN + tid] : -INFINITY;
  if (tid < 3) firsts_s[tid] = EE;
  __syncthreads();
  // stable top-3 (ties -> lowest index), parallel max-reduce per round
  for (int s = 0; s < 3; s++) {
    float v = key_s[tid];
    if ((s > 0 && tid == starts_s[0]) || (s > 1 && tid == starts_s[1])) v = -INFINITY;
    int idx = tid;
#pragma unroll
    for (int off = 32; off > 0; off >>= 1) {
      float ov = __shfl_xor(v, off, 64);
      int oi = __shfl_xor(idx, off, 64);
      if (ov > v || (ov == v && oi < idx)) { v = ov; idx = oi; }
    }
    if (lane == 0) { redv[wid] = v; redi[wid] = idx; }
    __syncthreads();
    if (tid == 0) {
      float bv = redv[0]; int bi = redi[0];
#pragma unroll
      for (int w = 1; w < 4; w++)
        if (redv[w] > bv || (redv[w] == bv && redi[w] < bi)) { bv = redv[w]; bi = redi[w]; }
      starts_s[s] = bi;
    }
    __syncthreads();
  }
  // first valid outgoing edge per start
  for (int e = tid; e < EE; e += 256) {
    int s = edge[e];
    int d = edge[EE + e];
    if (batch[d] == b) {
#pragma unroll
      for (int j = 0; j < 3; j++)
        if (s == starts_s[j]) atomicMin(&firsts_s[j], e);
    }
  }
  // batch-node list (deterministic order)
  if (tid == 64) {
    int c = 0;
    for (int n = 0; n < NN; n++)
      if (batch[n] == b) list[b * NN + c++] = n;
    meta[b * 16 + 10] = c;
  }
  __syncthreads();
  if (tid == 0) {
    int c = 0;
#pragma unroll
    for (int j = 0; j < 3; j++) {
      int f = firsts_s[j];
      meta[b * 16 + j] = starts_s[j];
      meta[b * 16 + 3 + j] = f;
      meta[b * 16 + 6 + j] = edge[EE + (f < EE ? f : EE - 1)];
      c += (f < EE) ? 1 : 0;
    }
    meta[b * 16 + 9] = c;
  }
}

// ---------- 5c. agg + fallback, parallel over B x H ----------
__global__ __launch_bounds__(256) void k_aggfall(const float* __restrict__ nf,
                                                 const float* __restrict__ npj,
                                                 const int* __restrict__ meta,
                                                 const int* __restrict__ list,
                                                 float* __restrict__ agg,
                                                 float* __restrict__ fallb) {
  const int b = blockIdx.y;
  const int col = blockIdx.x * 256 + threadIdx.x;
  const int* m = meta + b * 16;
  const int cnt = m[9], cntn = m[10];
  float a = 0.f;
#pragma unroll
  for (int j = 0; j < 3; j++)
    if (m[3 + j] < EE)
      a += 0.5f * (nf[(size_t)m[j] * H + col] + nf[(size_t)m[6 + j] * H + col]);
  agg[(size_t)b * H + col] = a / (float)(cnt > 0 ? cnt : 1);
  float f = 0.f;
  for (int i = 0; i < cntn; i++) f += npj[(size_t)list[b * NN + i] * H + col];
  fallb[(size_t)b * H + col] = f / (float)(cntn > 0 ? cntn : 1);
}

// ---------- 6. select h vs fallback, LayerNorm, write out ----------
__global__ __launch_bounds__(256) void k_finalize(const float* __restrict__ hb,
                                                  const float* __restrict__ fallb,
                                                  const int* __restrict__ meta,
                                                  const float* __restrict__ g,
                                                  const float* __restrict__ beta,
                                                  float* __restrict__ out) {
  const int b = blockIdx.x;
  const int tid = threadIdx.x;
  const int wid = tid >> 6, lane = tid & 63;
  __shared__ float red[4];
  const float* src = (meta[b * 16 + 9] > 0) ? &hb[(size_t)b * H] : &fallb[(size_t)b * H];
  float v[16];
  float s = 0.f;
#pragma unroll
  for (int i = 0; i < 16; i++) {
    v[i] = src[tid + i * 256];
    s += v[i];
  }
#pragma unroll
  for (int off = 32; off > 0; off >>= 1) s += __shfl_xor(s, off, 64);
  if (lane == 0) red[wid] = s;
  __syncthreads();
  float mu = (red[0] + red[1] + red[2] + red[3]) * (1.f / H);
  float q = 0.f;
#pragma unroll
  for (int i = 0; i < 16; i++) {
    float d = v[i] - mu;
    q = fmaf(d, d, q);
  }
  __syncthreads();  // red reuse
#pragma unroll
  for (int off = 32; off > 0; off >>= 1) q += __shfl_xor(q, off, 64);
  if (lane == 0) red[wid] = q;
  __syncthreads();
  float var = (red[0] + red[1] + red[2] + red[3]) * (1.f / H);
  float inv = 1.f / sqrtf(var + 1e-5f);
#pragma unroll
  for (int i = 0; i < 16; i++) {
    int col = tid + i * 256;
    out[(size_t)b * H + col] = (v[i] - mu) * inv * g[col] + beta[col];
  }
}

extern "C" void kernel_launch(void* const* d_in, const int* in_sizes, int n_in,
                              void* d_out, int out_size, void* d_ws, size_t ws_size,
                              hipStream_t stream) {
  (void)in_sizes; (void)n_in; (void)out_size;
  const float* query = (const float*)d_in[0];
  const float* nf    = (const float*)d_in[1];
  const float* Wq = (const float*)d_in[2];
  const float* bq = (const float*)d_in[3];
  const float* Wn = (const float*)d_in[4];
  const float* bn = (const float*)d_in[5];
  const float* W1 = (const float*)d_in[6];
  const float* b1 = (const float*)d_in[7];
  const float* W2 = (const float*)d_in[8];
  const float* b2 = (const float*)d_in[9];
  const float* lng = (const float*)d_in[10];
  const float* lnb = (const float*)d_in[11];
  const int* edge  = (const int*)d_in[12];
  const int* batch = (const int*)d_in[13];

  char* ws = (char*)d_ws;
  unsigned short* nfhi = (unsigned short*)(ws + OFF_NFHI);
  unsigned short* nflo = (unsigned short*)(ws + OFF_NFLO);
  float* qp    = (float*)(ws + OFF_QP);
  float* npj   = (float*)(ws + OFF_NPJ);
  float* agg   = (float*)(ws + OFF_AGG);
  float* fallb = (float*)(ws + OFF_FALLB);
  float* tbuf  = (float*)(ws + OFF_T);
  float* hbuf  = (float*)(ws + OFF_HB);
  float* keyb  = (float*)(ws + OFF_KEY);
  int*   meta  = (int*)(ws + OFF_META);
  int*   list  = (int*)(ws + OFF_LIST);
  float* npjp  = (float*)(ws + OFF_NPJP);

  // k-split factor limited by available workspace (4096 must divide ks*64)
  size_t per = (size_t)NN * H * 4u;
  int ks = 1;
  if (ws_size >= (size_t)OFF_NPJP + 8 * per) ks = 8;
  else if (ws_size >= (size_t)OFF_NPJP + 4 * per) ks = 4;
  else if (ws_size >= (size_t)OFF_NPJP + 2 * per) ks = 2;
  int nchunks = 64 / ks;

  k_split_nf<<<dim3(NPAD * (H / 4) / 256), dim3(256), 0, stream>>>(nf, nfhi, nflo);
  k_gemm_m8<<<dim3(512), dim3(256), 0, stream>>>(query, Wq, bq, qp, 0);
  k_npj_mfma<<<dim3(64 * ks), dim3(512), 0, stream>>>(nfhi, nflo, Wn, npjp, nchunks);
  k_npj_reduce<<<dim3(NN * H / 256), dim3(256), 0, stream>>>(npjp, bn, npj, ks);
  k_sim<<<dim3(NN), dim3(256), 0, stream>>>(qp, npj, batch, keyb);
  k_topedges<<<dim3(BB), dim3(256), 0, stream>>>(keyb, edge, batch, meta, list);
  k_aggfall<<<dim3(16, BB), dim3(256), 0, stream>>>(nf, npj, meta, list, agg, fallb);
  k_gemm_m8<<<dim3(512), dim3(256), 0, stream>>>(agg, W1, b1, tbuf, 1);
  k_gemm_m8<<<dim3(512), dim3(256), 0, stream>>>(tbuf, W2, b2, hbuf, 0);
  k_finalize<<<dim3(BB), dim3(256), 0, stream>>>(hbuf, fallb, meta, lng, lnb, (float*)d_out);
}